// Round 9
// baseline (2687.300 us; speedup 1.0000x reference)
//
#include <hip/hip_runtime.h>

typedef _Float16 f16;
typedef _Float16 f16x8 __attribute__((ext_vector_type(8)));
typedef _Float16 f16x4 __attribute__((ext_vector_type(4)));
typedef float f32x4 __attribute__((ext_vector_type(4)));

// ---------------------------------------------------------------------------
// ROUND 17: attack BYTES, not rate. Law confirmed 6x: time = per-CU staged
// bytes / ~6.3 B/cyc/CU (r13 up-scaled it: 1.5MB->109us; r9/r11/r14/r16 at
// 1.15MB -> 75-80us; rate invariant to transport/waits/occupancy/address
// pattern). FETCH 38MB shows L2 reuse works; HBM 0.5-2.8 TB/s; MFMA/VALU/LDS
// idle -> binder is the CU-side VMEM request pipe (~10 cyc per 64B line/CU;
// 1152 lines/iter = 11.7k cyc/iter, fits every round incl. r12).
// This round: BM=256 x BN=128 (grid 256, 1 block/CU, all CUs active):
// staged = 16.8MB*8(X) + 2MB*32(W) + 16.8MB(lora) = 215MB -> 0.84MB/CU
// (-27%). BK=32 so dbuf staging = 53.2KB static LDS (r15's 104KB build
// was the likely container-killer). 64B-row swizzle = r11/r13-validated
// algebra. Ascending 32-elem K-blocks -> r9-identical accumulation order.
// K-tiled operand layouts (r16 producers) retained.
// Predict: 76 -> 50-60us/layer, total ~1.05-1.15ms. If ~75us again: the
// per-CU-bytes law is falsified -> decisive.
// ---------------------------------------------------------------------------

// ---------------------------------------------------------------------------
// Dtype probe: scales true values lie in [0.01, 0.06]. Writes mode:
// 0=f16, 1=bf16, 2=f32. Graph-safe (no host sync).
// ---------------------------------------------------------------------------
__global__ void detect_kernel(const unsigned short* __restrict__ sc, int* __restrict__ mode)
{
    if (threadIdx.x != 0 || blockIdx.x != 0) return;
    bool ok16 = true, okbf = true;
    for (int i = 0; i < 64; i++) {
        const unsigned short b = sc[i];
        union { unsigned short u; f16 h; } ch; ch.u = b;
        const float fv = (float)ch.h;
        if (!(fv > 0.008f && fv < 0.062f)) ok16 = false;
        union { unsigned int u; float f; } cb; cb.u = ((unsigned int)b) << 16;
        if (!(cb.f > 0.008f && cb.f < 0.062f)) okbf = false;
    }
    *mode = ok16 ? 0 : (okbf ? 1 : 2);
}

__device__ __forceinline__ float load_half_like(const void* p, int i, int mode)
{
    if (mode == 0) return (float)((const f16*)p)[i];
    if (mode == 1) {
        union { unsigned int u; float f; } c;
        c.u = ((unsigned int)((const unsigned short*)p)[i]) << 16;
        return c.f;
    }
    return ((const float*)p)[i];
}

// ---------------------------------------------------------------------------
// Prep: dequant 4-bit -> f16 weights (f16 code math, f32 scale mul, round
// once -- matches ref), lora_A -> f16, lora_B*0.125 -> f16, x -> f16,
// biases -> f32. f16 operand outputs in K-TILED layout (r16):
//   W_t:  li*1048576 + kt*65536  + col*64 + kc   (kt = k>>6, kc = k&63)
//   A_t:  li*32768   + kt*2048   + p*64   + kc
//   x_t:            kt*524288    + row*64 + kc
// ---------------------------------------------------------------------------
__global__ void prep_kernel(const float* __restrict__ x, const int* __restrict__ qw,
                            const void* __restrict__ scales, const void* __restrict__ biases,
                            const float* __restrict__ lA, const float* __restrict__ lB,
                            const int* __restrict__ modep,
                            f16* __restrict__ Wdq, f16* __restrict__ A16,
                            f16* __restrict__ B16, f16* __restrict__ x16,
                            float* __restrict__ bias32)
{
    const int bid = blockIdx.x, tid = threadIdx.x;
    if (bid < 3840) {
        const int md = *modep;
        const int g = bid * 256 + tid;                 // group id; scale idx == g
        const float s = load_half_like(scales, g, md);
        const int4* qp = (const int4*)(qw + (size_t)g * 16);
        f16x8 w0, w1;
        #pragma unroll
        for (int v = 0; v < 4; v++) {
            const int4 q4 = qp[v];
            const int qs[4] = {q4.x, q4.y, q4.z, q4.w};
            #pragma unroll
            for (int j = 0; j < 4; j++) {
                f16 t = (f16)qs[j];
                t = t * (f16)(2.0f / 15.0f);           // f16 mul (matches ref)
                t = t - (f16)1.0f;                     // f16 sub
                const f16 w = (f16)((float)t * s);     // f32 scale mul, round once
                if (v < 2) w0[v * 4 + j] = w; else w1[(v - 2) * 4 + j] = w;
            }
        }
        // tiled dest: row = g>>6 (li*1024+col), grp = g&63 -> k0 = grp*16
        const int row = g >> 6;
        const int li  = row >> 10;
        const int col = row & 1023;
        const int grp = g & 63;
        const size_t dst = (size_t)li * 1048576 + (size_t)(grp >> 2) * 65536
                         + (size_t)col * 64 + ((grp & 3) << 4);
        *(f16x8*)(Wdq + dst) = w0;
        *(f16x8*)(Wdq + dst + 8) = w1;
    } else if (bid < 4320) {
        const int i = (bid - 3840) * 1024 + tid * 4;   // li*32768 + p*1024 + k
        const float4 a = *(const float4*)(lA + i);
        f16x4 o = {(f16)a.x, (f16)a.y, (f16)a.z, (f16)a.w};
        const int li = i >> 15, j = i & 32767;
        const int p = j >> 10, k = j & 1023;
        *(f16x4*)(A16 + (size_t)li * 32768 + (size_t)(k >> 6) * 2048
                      + (size_t)p * 64 + (k & 63)) = o;
    } else if (bid < 4800) {
        const int i = (bid - 4320) * 1024 + tid * 4;
        const float4 a = *(const float4*)(lB + i);
        f16x4 o = {(f16)(0.125f * a.x), (f16)(0.125f * a.y),
                   (f16)(0.125f * a.z), (f16)(0.125f * a.w)};
        *(f16x4*)(B16 + i) = o;                        // [col][32] layout kept
    } else if (bid < 12992) {
        const int row = bid - 4800;                    // one row per block
        const int k = tid * 4;
        const float4 a = *(const float4*)(x + (size_t)row * 1024 + k);
        f16x4 o = {(f16)a.x, (f16)a.y, (f16)a.z, (f16)a.w};
        *(f16x4*)(x16 + (size_t)(k >> 6) * 524288 + (size_t)row * 64 + (k & 63)) = o;
    } else {
        const int md = *modep;
        const int i = (bid - 12992) * 1024 + tid * 4;
        float4 o;
        o.x = load_half_like(biases, i, md);
        o.y = load_half_like(biases, i + 1, md);
        o.z = load_half_like(biases, i + 2, md);
        o.w = load_half_like(biases, i + 3, md);
        *(float4*)(bias32 + i) = o;
    }
}

// global -> LDS direct DMA, 16B per lane (dest: wave-uniform base + lane*16B)
__device__ __forceinline__ void gl_lds16(const f16* g, f16* l)
{
    __builtin_amdgcn_global_load_lds(
        (const __attribute__((address_space(1))) void*)g,
        (__attribute__((address_space(3))) void*)l, 16, 0, 0);
}

// ---------------------------------------------------------------------------
// Fused QLoRA layer. BM=256 BN=128 BK=32, 512 thr / 8 waves (4M x 2N bands),
// grid 256 = 1 block/CU. 2-phase barrier pipeline (r9 skeleton), 53.2KB LDS
// dbuf, K-tiled sources. 64B-row swizzle: LDS[r][c]=G[r][c^(r&3)] (write via
// pre-swizzled source chunk, DMA dest linear); frag read chunk q2^(r&3)
// (r11/r13-validated). 32 ascending K-blocks -> r9-identical accumulation.
// ---------------------------------------------------------------------------
__global__ __launch_bounds__(512, 1)
void layer_kernel(const f16* __restrict__ X16, const f16* __restrict__ W,
                  const f16* __restrict__ AL, const f16* __restrict__ BL,
                  const float* __restrict__ biasL, const float* __restrict__ resid,
                  float* __restrict__ out32, f16* __restrict__ out16, int do_relu)
{
    __shared__ __align__(16) f16 lds[26624];   // 53,248B: 2 x (sA16K|sB8K|sL2K)

    const int tid  = threadIdx.x;
    const int lane = tid & 63;
    const int wv   = tid >> 6;          // wave 0..7
    const int wy   = wv >> 1;           // 0..3: 64-row band
    const int wx   = wv & 1;            // 0..1: 64-col half
    const int by   = blockIdx.x & 31;   // row block (32) -> XCD = bid%8 = by%8
    const int bx   = blockIdx.x >> 5;   // col block (8)
    const int row0 = by << 8;           // 256 rows
    const int col0 = bx << 7;           // 128 cols

    // staging: DMA dest LINEAR; source chunk pre-swizzled (c ^ row&3) within
    // the row's 64B half-slice. lr4 = row within 16-row instr.
    const int lr4 = lane >> 2;
    const int csw = (((lane & 3) ^ (lr4 & 3)) << 3);   // elems {0,8,16,24}

    // fragment reads: row r wants logical chunk q2 -> phys chunk q2^(r&3)
    const int m15 = lane & 15;
    const int q2  = lane >> 4;                          // 0..3
    const int po  = ((q2 ^ (m15 & 3)) << 3);            // phys col (elems)
    const int q8  = q2 << 3;

    f32x4 acc[4][4] = {};
    f32x4 tacc[2][2] = {};

    // buffer (f16 elems): sA[256][32] @0 | sB[128][32] @8192 | sL[32][32] @12288
    auto stage = [&](f16* buf, int ks) {
        const int kt64 = ks >> 1;
        const int kb   = ((ks & 1) << 5) + csw;
        const f16* Xt = X16 + (size_t)kt64 * 524288;
        const f16* Wt = W   + (size_t)kt64 * 65536;
        const f16* At = AL  + (size_t)kt64 * 2048;
        #pragma unroll
        for (int i = 0; i < 2; i++)
            gl_lds16(Xt + (size_t)(row0 + wv * 32 + i * 16 + lr4) * 64 + kb,
                     buf + (wv * 32 + i * 16) * 32);
        gl_lds16(Wt + (size_t)(col0 + wv * 16 + lr4) * 64 + kb,
                 buf + 8192 + (wv * 16) * 32);
        if (wv < 2)
            gl_lds16(At + (size_t)(wv * 16 + lr4) * 64 + kb,
                     buf + 12288 + (wv * 16) * 32);
    };

    stage(lds, 0);                       // prologue: step 0 in flight

    for (int ks = 0; ks < 32; ks++) {
        __syncthreads();                 // drains vmcnt(0): buf[ks&1] staged
        const f16* cur = lds + (ks & 1) * 13312;
        const f16* sA = cur;
        const f16* sB = cur + 8192;
        const f16* sL = cur + 12288;

        if (ks < 31) stage(lds + ((ks + 1) & 1) * 13312, ks + 1);

        f16x8 af[4], bf[4], lf[2];
        #pragma unroll
        for (int mi = 0; mi < 4; mi++)
            af[mi] = *(const f16x8*)(sA + (wy * 64 + mi * 16 + m15) * 32 + po);
        #pragma unroll
        for (int ni = 0; ni < 4; ni++)
            bf[ni] = *(const f16x8*)(sB + (wx * 64 + ni * 16 + m15) * 32 + po);
        #pragma unroll
        for (int pi = 0; pi < 2; pi++)
            lf[pi] = *(const f16x8*)(sL + (pi * 16 + m15) * 32 + po);

        #pragma unroll
        for (int mi = 0; mi < 4; mi++)
            #pragma unroll
            for (int ni = 0; ni < 4; ni++)
                acc[mi][ni] = __builtin_amdgcn_mfma_f32_16x16x32_f16(af[mi], bf[ni], acc[mi][ni], 0, 0, 0);
        // lora stage-1: wave (wy,wx) owns rows wy*64+wx*32..+31 = frags 2wx,2wx+1
        #pragma unroll
        for (int mi = 0; mi < 2; mi++)
            #pragma unroll
            for (int pi = 0; pi < 2; pi++)
                tacc[mi][pi] = __builtin_amdgcn_mfma_f32_16x16x32_f16(af[2 * wx + mi], lf[pi], tacc[mi][pi], 0, 0, 0);
    }

    // ---- epilogue: lora stage-2 ----
    __syncthreads();
    float* Tl = (float*)lds;   // [256][33] f32 (33.8KB), aliases staging
    const int q4 = q2 << 2;
    {
        #pragma unroll
        for (int mi = 0; mi < 2; mi++)
            #pragma unroll
            for (int pi = 0; pi < 2; pi++)
                #pragma unroll
                for (int r = 0; r < 4; r++)
                    Tl[(wy * 64 + wx * 32 + mi * 16 + q4 + r) * 33 + pi * 16 + m15] = tacc[mi][pi][r];
    }
    __syncthreads();

    f16x8 tf[4];    // T in A-fragment layout (k = lora dim, K=32 -> one k-step)
    #pragma unroll
    for (int mi = 0; mi < 4; mi++) {
        const float* tp = Tl + (wy * 64 + mi * 16 + m15) * 33 + q8;
        f16x8 v;
        #pragma unroll
        for (int j = 0; j < 8; j++) v[j] = (f16)tp[j];
        tf[mi] = v;
    }
    f16x8 bfr[4]; float bb[4];
    #pragma unroll
    for (int ni = 0; ni < 4; ni++) {
        const int colg = col0 + wx * 64 + ni * 16 + m15;
        bfr[ni] = *(const f16x8*)(BL + (size_t)colg * 32 + q8);  // pre-scaled 0.125
        bb[ni] = biasL[colg];
    }
    #pragma unroll
    for (int mi = 0; mi < 4; mi++)
        #pragma unroll
        for (int ni = 0; ni < 4; ni++) {
            #pragma unroll
            for (int r = 0; r < 4; r++)
                acc[mi][ni][r] += bb[ni];      // f32 bias add (ref promotes to f32)
            acc[mi][ni] = __builtin_amdgcn_mfma_f32_16x16x32_f16(tf[mi], bfr[ni], acc[mi][ni], 0, 0, 0);
        }

    // ---- epilogue: coalesced store through LDS ----
    __syncthreads();   // all waves done with Tl before LDS reuse
    if (out16) {
        // f16 path (j=0/1): relu; TILED dest = panel 2bx+p, contiguous 32KB
        // slab [row0..row0+255]x64. Per-panel repack ot[256][72] (36.9KB).
        f16* ot = lds;
        #pragma unroll
        for (int p = 0; p < 2; p++) {
            if (wx == p) {
                #pragma unroll
                for (int mi = 0; mi < 4; mi++)
                    #pragma unroll
                    for (int ni = 0; ni < 4; ni++)
                        #pragma unroll
                        for (int r = 0; r < 4; r++) {
                            float v = acc[mi][ni][r];
                            if (do_relu) v = fmaxf(v, 0.0f);
                            ot[(wy * 64 + mi * 16 + q4 + r) * 72 + ni * 16 + m15] = (f16)v;
                        }
            }
            __syncthreads();
            f16* op = out16 + (size_t)(2 * bx + p) * 524288 + (size_t)row0 * 64;
            const int rr = tid >> 3;            // 0..63
            const int cc = (tid & 7) << 3;      // 16B chunks within 64-col row
            #pragma unroll
            for (int it = 0; it < 4; it++) {
                const int r = it * 64 + rr;
                *(f16x8*)(op + (size_t)r * 64 + cc) = *(const f16x8*)(ot + r * 72 + cc);
            }
            if (p == 0) __syncthreads();
        }
    } else {
        // f32 path (j=2): four 64-row bands via otf[64][132] f32 (33.8KB);
        // coalesced resid read + coalesced f32 store (h32 stays LINEAR).
        float* otf = (float*)lds;
        #pragma unroll
        for (int q = 0; q < 4; q++) {
            if (wy == q) {
                #pragma unroll
                for (int mi = 0; mi < 4; mi++)
                    #pragma unroll
                    for (int ni = 0; ni < 4; ni++)
                        #pragma unroll
                        for (int r = 0; r < 4; r++)
                            otf[(mi * 16 + q4 + r) * 132 + wx * 64 + ni * 16 + m15] = acc[mi][ni][r];
            }
            __syncthreads();
            const int rr = tid >> 5;            // 0..15
            const int cc = (tid & 31) << 2;     // f32 elems, 16B chunks
            #pragma unroll
            for (int it = 0; it < 4; it++) {
                const int r = it * 16 + rr;
                f32x4 v = *(const f32x4*)(otf + r * 132 + cc);
                const size_t gidx = (size_t)(row0 + q * 64 + r) * 1024 + col0 + cc;
                const f32x4 rs = *(const f32x4*)(resid + gidx);
                v += rs;
                *(f32x4*)(out32 + gidx) = v;
            }
            if (q < 3) __syncthreads();
        }
    }
}

// ---------------------------------------------------------------------------
// LayerNorm over rows of h (f32 linear, in place) + f16 copy in TILED layout
// for the next GEMM input.
// ---------------------------------------------------------------------------
__global__ void ln_kernel(float* __restrict__ h, f16* __restrict__ h16,
                          const float* __restrict__ g, const float* __restrict__ b)
{
    const int row = blockIdx.x, tid = threadIdx.x;
    float* hp = h + (size_t)row * 1024;
    const int c = tid * 4;
    const float4 v = *(const float4*)(hp + c);
    float s = v.x + v.y + v.z + v.w;
    #pragma unroll
    for (int off = 32; off > 0; off >>= 1) s += __shfl_down(s, off);
    __shared__ float r1[4], r2[4];
    const int wv = tid >> 6, lane = tid & 63;
    if (lane == 0) r1[wv] = s;
    __syncthreads();
    const float mu = (r1[0] + r1[1] + r1[2] + r1[3]) * (1.0f / 1024.0f);
    const float dx = v.x - mu, dy = v.y - mu, dz = v.z - mu, dw = v.w - mu;
    float s2 = dx * dx + dy * dy + dz * dz + dw * dw;
    #pragma unroll
    for (int off = 32; off > 0; off >>= 1) s2 += __shfl_down(s2, off);
    if (lane == 0) r2[wv] = s2;
    __syncthreads();
    const float var = (r2[0] + r2[1] + r2[2] + r2[3]) * (1.0f / 1024.0f);
    const float rs = 1.0f / sqrtf(var + 1e-5f);
    float4 o;
    o.x = dx * rs * g[c]     + b[c];
    o.y = dy * rs * g[c + 1] + b[c + 1];
    o.z = dz * rs * g[c + 2] + b[c + 2];
    o.w = dw * rs * g[c + 3] + b[c + 3];
    *(float4*)(hp + c) = o;
    f16x4 o16 = {(f16)o.x, (f16)o.y, (f16)o.z, (f16)o.w};
    *(f16x4*)(h16 + (size_t)(c >> 6) * 524288 + (size_t)row * 64 + (c & 63)) = o16;
}

// ---------------------------------------------------------------------------
// ws layout (~64 MB): mode@0 | bias32@64 | Wdq@65536 | A16 | B16 | fA | fB
// f32 residual carrier lives in d_out (overwritten fully every call).
// ---------------------------------------------------------------------------
extern "C" void kernel_launch(void* const* d_in, const int* in_sizes, int n_in,
                              void* d_out, int out_size, void* d_ws, size_t ws_size,
                              hipStream_t stream)
{
    const float* x      = (const float*)d_in[0];
    const int*   qw     = (const int*)d_in[1];
    const void*  scales = d_in[2];
    const void*  biases = d_in[3];
    const float* lA     = (const float*)d_in[4];
    const float* lB     = (const float*)d_in[5];
    const float* lng    = (const float*)d_in[6];
    const float* lnb    = (const float*)d_in[7];
    float* out = (float*)d_out;

    char* ws = (char*)d_ws;
    int*   mode   = (int*)(ws);
    float* bias32 = (float*)(ws + 64);
    f16* Wdq = (f16*)(ws + 65536u);
    f16* A16 = (f16*)(ws + 31522816u);
    f16* B16 = (f16*)(ws + 32505856u);
    f16* fA  = (f16*)(ws + 33488896u);
    f16* fB  = (f16*)(ws + 50266112u);
    float* h32 = out;   // residual carrier in d_out

    detect_kernel<<<1, 64, 0, stream>>>((const unsigned short*)scales, mode);
    prep_kernel<<<13007, 256, 0, stream>>>(x, qw, scales, biases, lA, lB, mode,
                                           Wdq, A16, B16, fA, bias32);

    int li = 0;
    for (int blk = 0; blk < 6; blk++) {
        const float* resid = (blk == 0) ? x : h32;
        for (int j = 0; j < 3; j++, li++) {
            const int wl = li < 15 ? li : 14;      // JAX clamps q_w[15..17] -> 14
            const f16* in16 = (j == 1) ? fB : fA;
            f16* o16 = (j == 0) ? fB : (j == 1 ? fA : (f16*)nullptr);
            float* o32 = nullptr;
            const float* rz = nullptr;
            if (j == 2) { o32 = h32; rz = resid; }
            layer_kernel<<<256, 512, 0, stream>>>(in16,
                Wdq + (size_t)wl * 1048576,
                A16 + (size_t)wl * 32768,
                B16 + (size_t)wl * 32768,
                bias32 + (size_t)wl * 1024,
                rz, o32, o16, j < 2 ? 1 : 0);
        }
        if (blk < 5)
            ln_kernel<<<8192, 256, 0, stream>>>(h32, fA, lng + blk * 1024, lnb + blk * 1024);
    }
}